// Round 5
// baseline (335.546 us; speedup 1.0000x reference)
//
#include <hip/hip_runtime.h>
#include <hip/hip_bf16.h>

#define BB 8
#define NN 2048
#define DD 128

typedef __attribute__((ext_vector_type(8))) __bf16 bf16x8;
typedef __attribute__((ext_vector_type(4))) float f32x4;
typedef __attribute__((ext_vector_type(4))) int   i32x4;

static __device__ __forceinline__ unsigned short f2bf(float f) {
    union { float f; unsigned u; } v; v.f = f;
    unsigned r = (v.u + 0x7FFFu + ((v.u >> 16) & 1u)) >> 16;
    return (unsigned short)r;
}
static __device__ __forceinline__ float bf2f(unsigned short b) {
    union { unsigned u; float f; } v; v.u = ((unsigned)b) << 16;
    return v.f;
}

// ---------------------------------------------------------------------------
// kernP v2: blocks 0..4095 (4 rows each, 1 wave/row): lane l packs cols
// [l*32, l*32+32) of Ptilde = punct & mask_j into one word via int4 loads +
// in-lane bitpack (no ballots). Diagonal bit cleared HERE so downstream needs
// no pd subtraction. scale[i] = mask_i ? 1/max(popcount,1) : 0.
// Block 4096 casts combined weights Wc[e][k<128]=w_self, [k>=128]=w_punct.
// ---------------------------------------------------------------------------
__global__ __launch_bounds__(256) void kernP(
    const int* __restrict__ punct, const int* __restrict__ mask,
    const float* __restrict__ w_self, const float* __restrict__ w_punct,
    unsigned* __restrict__ pk, float* __restrict__ scale_g,
    unsigned short* __restrict__ wc)
{
    const int t = threadIdx.x;
    if (blockIdx.x == 4096) {
        for (int idx = t; idx < 128 * 256; idx += 256) {
            const int e = idx >> 8, k = idx & 255;
            const float v = (k < 128) ? w_self[e * 128 + k]
                                      : w_punct[e * 128 + (k - 128)];
            wc[idx] = f2bf(v);
        }
        return;
    }
    const int wave = t >> 6, lane = t & 63;
    const int row_g = blockIdx.x * 4 + wave;
    const int b = row_g >> 11;
    const int i = row_g & (NN - 1);

    const int* prow = punct + (size_t)row_g * NN + lane * 32;
    const int* mrow = mask + (size_t)b * NN + lane * 32;

    unsigned pp = 0, mm = 0;
    #pragma unroll
    for (int c = 0; c < 8; ++c) {          // 8 independent int4 loads each
        i32x4 pv = *(const i32x4*)(prow + c * 4);
        i32x4 mv = *(const i32x4*)(mrow + c * 4);
        pp |= (unsigned)((pv.x & 1) | ((pv.y & 1) << 1) | ((pv.z & 1) << 2) | ((pv.w & 1) << 3)) << (c * 4);
        mm |= (unsigned)((mv.x & 1) | ((mv.y & 1) << 1) | ((mv.z & 1) << 2) | ((mv.w & 1) << 3)) << (c * 4);
    }
    unsigned pw = pp & mm;
    if (lane == (i >> 5)) pw &= ~(1u << (i & 31));   // zero diagonal
    pk[(size_t)row_g * 64 + lane] = pw;

    int cnt = __popc(pw);
    #pragma unroll
    for (int o = 32; o > 0; o >>= 1) cnt += __shfl_xor(cnt, o, 64);
    if (lane == 0) {
        const int mi = mask[(size_t)b * NN + i];
        scale_g[row_g] = mi ? 1.f / (float)(cnt < 1 ? 1 : cnt) : 0.f;
    }
}

// ---------------------------------------------------------------------------
// kernD (step-0 prologue): dw0 = sigmoid(x.w_nw + b_nw) -> aw[:,0,:];
// ab[:, :128] = bf16(x); xwT = (dw0*x)^T  [B][D][N].
// ---------------------------------------------------------------------------
__global__ __launch_bounds__(256) void kernD(
    const float* __restrict__ x,
    const float* __restrict__ w_nw, const float* __restrict__ b_nw,
    float* __restrict__ aw_out,
    unsigned short* __restrict__ ab, unsigned short* __restrict__ xwT)
{
    __shared__ float wnw_l[DD];
    __shared__ float red[256];
    __shared__ float dw_l[64];
    __shared__ unsigned short xl[64 * 136];

    const int t  = threadIdx.x;
    const int n0 = blockIdx.x * 64;
    const int b  = n0 >> 11;
    const int nb = n0 & (NN - 1);

    if (t < DD) wnw_l[t] = w_nw[t];
    __syncthreads();

    const int row = t >> 2, q = t & 3;
    const float* xs = x + (size_t)(n0 + row) * DD + q * 32;
    float vals[32];
    float dp = 0.f;
    #pragma unroll
    for (int j = 0; j < 8; ++j) {
        f32x4 a = *(const f32x4*)(xs + j * 4);
        vals[j*4+0] = a.x; vals[j*4+1] = a.y; vals[j*4+2] = a.z; vals[j*4+3] = a.w;
        const float* wv = &wnw_l[q * 32 + j * 4];
        dp += a.x*wv[0] + a.y*wv[1] + a.z*wv[2] + a.w*wv[3];
    }
    red[t] = dp;
    __syncthreads();
    if (t < 64) {
        float s = red[4*t] + red[4*t+1] + red[4*t+2] + red[4*t+3] + b_nw[0];
        float dv = 1.f / (1.f + __expf(-s));
        dw_l[t] = dv;
        aw_out[(size_t)b * 2 * NN + nb + t] = dv;
    }
    __syncthreads();

    unsigned pb[16];
    #pragma unroll
    for (int j = 0; j < 16; ++j)
        pb[j] = f2bf(vals[2*j]) | ((unsigned)f2bf(vals[2*j+1]) << 16);
    {
        i32x4* dst = (i32x4*)(ab + (size_t)(n0 + row) * 256 + q * 32);
        i32x4 v0 = {(int)pb[0],(int)pb[1],(int)pb[2],(int)pb[3]};
        i32x4 v1 = {(int)pb[4],(int)pb[5],(int)pb[6],(int)pb[7]};
        i32x4 v2 = {(int)pb[8],(int)pb[9],(int)pb[10],(int)pb[11]};
        i32x4 v3 = {(int)pb[12],(int)pb[13],(int)pb[14],(int)pb[15]};
        dst[0]=v0; dst[1]=v1; dst[2]=v2; dst[3]=v3;
    }
    const float dwv = dw_l[row];
    #pragma unroll
    for (int j = 0; j < 16; ++j)
        pb[j] = f2bf(vals[2*j]*dwv) | ((unsigned)f2bf(vals[2*j+1]*dwv) << 16);
    {
        i32x4 v0 = {(int)pb[0],(int)pb[1],(int)pb[2],(int)pb[3]};
        i32x4 v1 = {(int)pb[4],(int)pb[5],(int)pb[6],(int)pb[7]};
        i32x4 v2 = {(int)pb[8],(int)pb[9],(int)pb[10],(int)pb[11]};
        i32x4 v3 = {(int)pb[12],(int)pb[13],(int)pb[14],(int)pb[15]};
        i32x4* ld = (i32x4*)&xl[row * 136 + q * 32];
        ld[0]=v0; ld[1]=v1; ld[2]=v2; ld[3]=v3;
    }
    __syncthreads();
    {
        const int d = t >> 1, half = t & 1;
        unsigned o[16];
        #pragma unroll
        for (int k = 0; k < 16; ++k) {
            const int r0 = half * 32 + 2 * k;
            o[k] = (unsigned)xl[r0 * 136 + d] | ((unsigned)xl[(r0+1) * 136 + d] << 16);
        }
        i32x4 v0 = {(int)o[0],(int)o[1],(int)o[2],(int)o[3]};
        i32x4 v1 = {(int)o[4],(int)o[5],(int)o[6],(int)o[7]};
        i32x4 v2 = {(int)o[8],(int)o[9],(int)o[10],(int)o[11]};
        i32x4 v3 = {(int)o[12],(int)o[13],(int)o[14],(int)o[15]};
        i32x4* dst = (i32x4*)(xwT + (size_t)(b * DD + d) * NN + nb + half * 32);
        dst[0]=v0; dst[1]=v1; dst[2]=v2; dst[3]=v3;
    }
}

// ---------------------------------------------------------------------------
// kernC2: phase 1 only — Z = bitP @ xwT (diag already zeroed in pk), then
// Zs = scale*Z as bf16 into ab[:, 128:256]. 32 rows/block, 512 blocks
// (2 blocks/CU for latency hiding). Zero barriers in the K-loop.
// ---------------------------------------------------------------------------
__global__ __launch_bounds__(256) void kernC2(
    const unsigned* __restrict__ pk, const float* __restrict__ scale_g,
    const unsigned short* __restrict__ xwT,   // [B][D][N]
    unsigned short* __restrict__ ab)          // [B*N][256], writes cols 128..255
{
    __shared__ unsigned pPk[32 * 68];
    __shared__ float scale_l[32];

    const int t  = threadIdx.x;
    const int b  = blockIdx.x >> 6;
    const int i0 = (blockIdx.x & 63) * 32;
    const size_t rg0 = (size_t)b * NN + i0;

    #pragma unroll
    for (int r = 0; r < 2; ++r) {
        const int u = r * 256 + t;          // 0..511 vec4 loads
        const int row = u >> 4;
        const int wq  = (u & 15) * 4;
        i32x4 v = *(const i32x4*)(pk + (rg0 + row) * 64 + wq);
        *(i32x4*)&pPk[row * 68 + wq] = v;
    }
    if (t < 32) scale_l[t] = scale_g[rg0 + t];
    __syncthreads();

    const int wn = t >> 6, lane = t & 63;
    const int quad = lane >> 4, l16 = lane & 15;
    const unsigned short* xwTb = xwT + (size_t)b * DD * NN;

    f32x4 acc[2][2] = {};
    #pragma unroll 4
    for (int kk = 0; kk < 64; ++kk) {
        bf16x8 bfr[2];
        #pragma unroll
        for (int nt = 0; nt < 2; ++nt) {
            const int d = wn*32 + nt*16 + l16;
            bfr[nt] = *(const bf16x8*)(xwTb + (size_t)d * NN + kk*32 + quad*8);
        }
        bf16x8 af[2];
        #pragma unroll
        for (int mt = 0; mt < 2; ++mt) {
            const unsigned w = pPk[(mt*16 + l16) * 68 + kk];
            const unsigned by = (w >> (quad * 8)) & 0xFFu;
            i32x4 ex;
            ex.x = ((by &   1u) ? 0x3F80 : 0) | ((by &   2u) ? 0x3F800000 : 0);
            ex.y = ((by &   4u) ? 0x3F80 : 0) | ((by &   8u) ? 0x3F800000 : 0);
            ex.z = ((by &  16u) ? 0x3F80 : 0) | ((by &  32u) ? 0x3F800000 : 0);
            ex.w = ((by &  64u) ? 0x3F80 : 0) | ((by & 128u) ? 0x3F800000 : 0);
            union { i32x4 i; bf16x8 h; } cv; cv.i = ex;
            af[mt] = cv.h;
        }
        #pragma unroll
        for (int mt = 0; mt < 2; ++mt)
            #pragma unroll
            for (int nt = 0; nt < 2; ++nt)
                acc[mt][nt] = __builtin_amdgcn_mfma_f32_16x16x32_bf16(af[mt], bfr[nt], acc[mt][nt], 0, 0, 0);
    }

    #pragma unroll
    for (int mt = 0; mt < 2; ++mt) {
        #pragma unroll
        for (int nt = 0; nt < 2; ++nt) {
            const int d = wn*32 + nt*16 + l16;
            #pragma unroll
            for (int r = 0; r < 4; ++r) {
                const int row = mt*16 + quad*4 + r;
                ab[(rg0 + row) * 256 + 128 + d] = f2bf(scale_l[row] * acc[mt][nt][r]);
            }
        }
    }
}

// ---------------------------------------------------------------------------
// kernF: out = relu([xbf|Zs] @ Wc^T + b_self) (K=256); epilogue writes x_out
// f32, dw_next -> aw_next, and (if want_next) ab_next[:, :128] = bf16(out)
// and xwT_next = (dw_next*out)^T.
// ---------------------------------------------------------------------------
__global__ __launch_bounds__(256) void kernF(
    const unsigned short* __restrict__ ab,    // [B*N][256]
    const unsigned short* __restrict__ wc,    // [128][256]
    const float* __restrict__ b_self,
    const float* __restrict__ w_nw, const float* __restrict__ b_nw,
    float* __restrict__ x_out, float* __restrict__ aw_next,
    unsigned short* __restrict__ ab_next, unsigned short* __restrict__ xwT_next,
    int want_next)
{
    __shared__ unsigned short xl[64 * 136];
    __shared__ float red[64 * 65];
    __shared__ float dw_l[64];

    const int t  = threadIdx.x;
    const int n0 = blockIdx.x * 64;
    const int b  = n0 >> 11;
    const int nb = n0 & (NN - 1);
    const size_t rg0 = (size_t)n0;

    const int wn = t >> 6, lane = t & 63;
    const int quad = lane >> 4, l16 = lane & 15;

    f32x4 acc[4][2] = {};
    #pragma unroll
    for (int kq = 0; kq < 8; ++kq) {
        bf16x8 b2[2];
        #pragma unroll
        for (int nt = 0; nt < 2; ++nt) {
            const int e = wn*32 + nt*16 + l16;
            b2[nt] = *(const bf16x8*)(wc + (size_t)e * 256 + kq*32 + quad*8);
        }
        bf16x8 a2[4];
        #pragma unroll
        for (int mt = 0; mt < 4; ++mt)
            a2[mt] = *(const bf16x8*)(ab + (rg0 + mt*16 + l16) * 256 + kq*32 + quad*8);
        #pragma unroll
        for (int mt = 0; mt < 4; ++mt)
            #pragma unroll
            for (int nt = 0; nt < 2; ++nt)
                acc[mt][nt] = __builtin_amdgcn_mfma_f32_16x16x32_bf16(a2[mt], b2[nt], acc[mt][nt], 0, 0, 0);
    }

    float bias[2], wnv[2];
    #pragma unroll
    for (int nt = 0; nt < 2; ++nt) {
        const int e = wn*32 + nt*16 + l16;
        bias[nt] = b_self[e];
        wnv[nt]  = w_nw[e];
    }
    #pragma unroll
    for (int mt = 0; mt < 4; ++mt) {
        #pragma unroll
        for (int r = 0; r < 4; ++r) {
            const int row = mt*16 + quad*4 + r;
            float p = 0.f;
            #pragma unroll
            for (int nt = 0; nt < 2; ++nt) {
                const int e = wn*32 + nt*16 + l16;
                float v = fmaxf(acc[mt][nt][r] + bias[nt], 0.f);
                x_out[(rg0 + row) * DD + e] = v;
                xl[row * 136 + e] = f2bf(v);
                p += v * wnv[nt];
            }
            red[row * 65 + wn*16 + l16] = p;
        }
    }
    __syncthreads();
    if (t < 64) {
        float s = b_nw[0];
        #pragma unroll 8
        for (int c = 0; c < 64; ++c) s += red[t * 65 + c];
        float dv = 1.f / (1.f + __expf(-s));
        dw_l[t] = dv;
        aw_next[(size_t)b * 2 * NN + nb + t] = dv;
    }
    __syncthreads();

    if (want_next) {
        {   // ab_next[:, :128] = bf16(x_new), coalesced from LDS
            const int row = t >> 2, q = t & 3;
            const i32x4* src = (const i32x4*)&xl[row * 136 + q * 32];
            i32x4 v0 = src[0], v1 = src[1], v2 = src[2], v3 = src[3];
            i32x4* dst = (i32x4*)(ab_next + (rg0 + row) * 256 + q * 32);
            dst[0]=v0; dst[1]=v1; dst[2]=v2; dst[3]=v3;
        }
        {   // xwT_next = (dw*x_new)^T
            const int d = t >> 1, half = t & 1;
            unsigned o[16];
            #pragma unroll
            for (int k = 0; k < 16; ++k) {
                const int r0 = half * 32 + 2 * k;
                const float lo = bf2f(xl[r0 * 136 + d]) * dw_l[r0];
                const float hi = bf2f(xl[(r0+1) * 136 + d]) * dw_l[r0+1];
                o[k] = f2bf(lo) | ((unsigned)f2bf(hi) << 16);
            }
            i32x4 v0 = {(int)o[0],(int)o[1],(int)o[2],(int)o[3]};
            i32x4 v1 = {(int)o[4],(int)o[5],(int)o[6],(int)o[7]};
            i32x4 v2 = {(int)o[8],(int)o[9],(int)o[10],(int)o[11]};
            i32x4 v3 = {(int)o[12],(int)o[13],(int)o[14],(int)o[15]};
            i32x4* dst = (i32x4*)(xwT_next + (size_t)(b * DD + d) * NN + nb + half * 32);
            dst[0]=v0; dst[1]=v1; dst[2]=v2; dst[3]=v3;
        }
    }
}

extern "C" void kernel_launch(void* const* d_in, const int* in_sizes, int n_in,
                              void* d_out, int out_size, void* d_ws, size_t ws_size,
                              hipStream_t stream) {
    const float* node   = (const float*)d_in[0];
    const int*   mask   = (const int*)  d_in[1];
    const int*   punct  = (const int*)  d_in[2];
    const float* w_nw   = (const float*)d_in[3];
    const float* b_nw   = (const float*)d_in[4];
    const float* w_self = (const float*)d_in[5];
    const float* b_self = (const float*)d_in[6];
    const float* w_punct= (const float*)d_in[7];

    float* xout = (float*)d_out;
    float* aw   = xout + (size_t)BB * NN * DD;

    char* w = (char*)d_ws;
    unsigned*       pk    = (unsigned*)w;                                 // 4 MB
    float*          scl   = (float*)(w + (4u<<20));                       // 64 KB
    unsigned short* wc    = (unsigned short*)(w + (4u<<20) + (64u<<10));  // 64 KB
    float*          awdum = (float*)(w + (4u<<20) + (128u<<10));          // 64 KB
    unsigned short* ab0   = (unsigned short*)(w + (5u<<20));              // 8 MB
    unsigned short* ab1   = (unsigned short*)(w + (13u<<20));             // 8 MB
    unsigned short* xwT0  = (unsigned short*)(w + (21u<<20));             // 4 MB
    unsigned short* xwT1  = (unsigned short*)(w + (25u<<20));             // 4 MB

    dim3 blk(256);
    kernP<<<dim3(4097), blk, 0, stream>>>(punct, mask, w_self, w_punct, pk, scl, wc);
    kernD<<<dim3(256), blk, 0, stream>>>(node, w_nw, b_nw, aw, ab0, xwT0);
    // step 0
    kernC2<<<dim3(512), blk, 0, stream>>>(pk, scl, xwT0, ab0);
    kernF<<<dim3(256), blk, 0, stream>>>(ab0, wc, b_self, w_nw, b_nw,
                                         xout, aw + NN, ab1, xwT1, 1);
    // step 1 (dw_next/tensors not needed: want_next=0, aw -> dummy)
    kernC2<<<dim3(512), blk, 0, stream>>>(pk, scl, xwT1, ab1);
    kernF<<<dim3(256), blk, 0, stream>>>(ab1, wc, b_self, w_nw, b_nw,
                                         xout, awdum, ab0, xwT0, 0);
}